// Round 1
// 441.663 us; speedup vs baseline: 1.0468x; 1.0468x over previous
//
#include <hip/hip_runtime.h>
#include <cstdint>
#include <cstddef>

// Problem constants: B=4, T=2048, H=1024, NH=16, HD=64, FF=4096, M=B*T=8192
typedef unsigned short u16;
typedef __attribute__((ext_vector_type(8))) __bf16 bf16x8;
typedef __attribute__((ext_vector_type(4))) __bf16 bf16x4;
typedef __attribute__((ext_vector_type(4))) float f32x4;
typedef __attribute__((ext_vector_type(4))) u16 u16x4;

#define MFMA(a, b, c) __builtin_amdgcn_mfma_f32_16x16x32_bf16((a), (b), (c), 0, 0, 0)

__device__ __forceinline__ u16 f2b(float f) {  // native RNE cvt (1-2 ops)
  union { __bf16 h; u16 u; } v;
  v.h = (__bf16)f;
  return v.u;
}

__device__ __forceinline__ void gld16(const void* g, void* l) {
  __builtin_amdgcn_global_load_lds(
      (__attribute__((address_space(1))) void*)(void*)(g),
      (__attribute__((address_space(3))) void*)(l), 16, 0, 0);
}

// Fragment-ordered layouts (per head, 131072 u16 = 2048x64):
// Q/K: element (t, hd): chunk ((t>>4)*2 + (hd>>5)), lane ((hd>>3)&3)*16 + (t&15),
//      byte-slot hd&7. MFMA lane l reads its 16B at chunk_base + l*16B.
__device__ __forceinline__ size_t qk_off(int t, int hd) {
  return (size_t)((((t >> 4) * 2 + (hd >> 5)) * 512)
                  + ((((hd >> 3) & 3) * 16 + (t & 15)) * 8) + (hd & 7));
}
// V: keys kk-permuted within 64-groups (kk = (t&15)*4 + ((t>>4)&3)) to match the
//    P-tile LDS packing; fragment order for PV B-operand reads.
__device__ __forceinline__ size_t v_off(int t, int hd) {
  int kk = ((t & 15) << 2) | ((t >> 4) & 3);
  return (size_t)(((t >> 6) * 4096)
                  + (((hd >> 4) * 2 + (kk >> 5)) * 512)
                  + ((((kk >> 3) & 3) * 16 + (hd & 15)) * 8) + (kk & 7));
}

// ---------------------------------------------------------------------------
// elementwise fp32 -> bf16 (vectorized x4)
__global__ void xconv(const float* __restrict__ in, u16* __restrict__ out, int n) {
  int i = (blockIdx.x * blockDim.x + threadIdx.x) * 4;
  if (i >= n) return;
  float4 v = *(const float4*)(in + i);
  u16x4 o;
  o[0] = f2b(v.x); o[1] = f2b(v.y); o[2] = f2b(v.z); o[3] = f2b(v.w);
  *(u16x4*)(out + i) = o;
}

// ---------------------------------------------------------------------------
// All weight transposes in ONE launch. W [K,N] fp32 -> Wt [N,K] bf16.
__global__ void wtrans_all(const float* __restrict__ Wq, const float* __restrict__ Wk,
                           const float* __restrict__ Wv, const float* __restrict__ W1,
                           const float* __restrict__ W2, u16* __restrict__ Wqkvt,
                           u16* __restrict__ W1t, u16* __restrict__ W2t) {
  __shared__ float tile[32][33];
  int blk = blockIdx.x;
  const float* W;
  u16* Wt;
  int Kd, Nd, nx;
  if (blk < 3072) {
    int s = blk >> 10;
    blk &= 1023;
    W = (s == 0) ? Wq : (s == 1) ? Wk : Wv;
    Wt = Wqkvt + (size_t)s * 1048576;
    Kd = 1024; Nd = 1024; nx = 32;
  } else if (blk < 7168) {
    blk -= 3072; W = W1; Wt = W1t; Kd = 1024; Nd = 4096; nx = 128;
  } else {
    blk -= 7168; W = W2; Wt = W2t; Kd = 4096; Nd = 1024; nx = 32;
  }
  int n0 = (blk % nx) * 32, k0 = (blk / nx) * 32;
  int tx = threadIdx.x, ty = threadIdx.y;
#pragma unroll
  for (int i = 0; i < 4; i++)
    tile[ty + i * 8][tx] = W[(size_t)(k0 + ty + i * 8) * Nd + n0 + tx];
  __syncthreads();
#pragma unroll
  for (int i = 0; i < 4; i++)
    Wt[(size_t)(n0 + ty + i * 8) * Kd + k0 + tx] = f2b(tile[tx][ty + i * 8]);
}

// ---------------------------------------------------------------------------
// Legacy 128x128 gemm (kept for MLP2: MODE 3 fp32 out = v + resid).
template <int MODE, int NW>
__global__ __launch_bounds__(NW * 64) void gemm_bt(
    const u16* __restrict__ A, const u16* __restrict__ Bt,
    const float* __restrict__ b0, const float* __restrict__ b1,
    const float* __restrict__ b2, void* __restrict__ outp,
    const float* __restrict__ resid, int N, int K, float scale) {
  constexpr int NT = NW * 64;
  constexpr int NTILE = (NW == 4) ? 4 : 2;
  __shared__ __attribute__((aligned(16))) u16 As[128 * 64];
  __shared__ __attribute__((aligned(16))) u16 Bs[128 * 64];
  const int tid = threadIdx.x;
  const int wid = tid >> 6, lane = tid & 63;
  const int g = lane >> 4, r = lane & 15;
  const int bm = blockIdx.y, bn = blockIdx.x;
  const int wrow = (NW == 4) ? (wid >> 1) * 64 : (wid >> 2) * 64;
  const int wcol = (NW == 4) ? (wid & 1) * 64 : (wid & 3) * 32;

  const f32x4 zero4 = {0.f, 0.f, 0.f, 0.f};
  f32x4 acc[4][NTILE];
#pragma unroll
  for (int i = 0; i < 4; i++)
#pragma unroll
    for (int j = 0; j < NTILE; j++) acc[i][j] = zero4;

  const size_t aBase = (size_t)bm * 128 * K;
  const size_t bBase = (size_t)bn * 128 * K;
  const int ko0 = ((0 * 4 + g) ^ (r & 7)) * 8;
  const int ko1 = ((1 * 4 + g) ^ (r & 7)) * 8;

  for (int k0 = 0; k0 < K; k0 += 64) {
    __syncthreads();
#pragma unroll
    for (int i = 0; i < 2048 / NT; i++) {
      const int c0 = i * NT;
      const int cc = (c0 + tid) & 1023;
      const int row = cc >> 3;
      const int js = ((cc & 7) ^ (row & 7)) * 8;
      if (c0 < 1024)
        gld16(A + aBase + (size_t)row * K + k0 + js, As + cc * 8);
      else
        gld16(Bt + bBase + (size_t)row * K + k0 + js, Bs + cc * 8);
    }
    __syncthreads();
#pragma unroll
    for (int kh = 0; kh < 2; kh++) {
      const int ko = kh ? ko1 : ko0;
      bf16x8 af[4], bfr[NTILE];
#pragma unroll
      for (int t = 0; t < 4; t++)
        af[t] = *(const bf16x8*)&As[(wrow + t * 16 + r) * 64 + ko];
#pragma unroll
      for (int t = 0; t < NTILE; t++)
        bfr[t] = *(const bf16x8*)&Bs[(wcol + t * 16 + r) * 64 + ko];
#pragma unroll
      for (int mt = 0; mt < 4; mt++)
#pragma unroll
        for (int nt = 0; nt < NTILE; nt++)
          acc[mt][nt] = MFMA(af[mt], bfr[nt], acc[mt][nt]);
    }
  }

#pragma unroll
  for (int mt = 0; mt < 4; mt++) {
#pragma unroll
    for (int nt = 0; nt < NTILE; nt++) {
      int col = bn * 128 + wcol + nt * 16 + r;
      float bv;
      if (MODE == 4) {
        int sec = col >> 10, hcol = col & 1023;
        bv = (sec == 0) ? b0[hcol] : (sec == 1) ? b1[hcol] : b2[hcol];
      } else {
        bv = b0[col];
      }
#pragma unroll
      for (int rr = 0; rr < 4; rr++) {
        int row = bm * 128 + wrow + mt * 16 + g * 4 + rr;
        float v = acc[mt][nt][rr] + bv;
        if (MODE == 2) {
          const float c1 = -2.3025850929940457f;
          const float c2 = c1 * 0.044715f;
          float t2 = v * v;
          float z = v * (c1 + c2 * t2);
          float sg = 1.0f / (1.0f + __builtin_amdgcn_exp2f(z));
          ((u16*)outp)[(size_t)row * N + col] = f2b(v * sg);
        } else if (MODE == 3) {
          ((float*)outp)[(size_t)row * N + col] = v + resid[(size_t)row * N + col];
        } else if (MODE == 4) {
          int sec = col >> 10, hcol = col & 1023;
          int head = hcol >> 6, hd = hcol & 63;
          int bb = row >> 11, t = row & 2047;
          size_t hbase = ((size_t)bb * 16 + head) * 131072;
          u16* qout = (u16*)outp;
          if (sec == 0) {
            qout[hbase + qk_off(t, hd)] = f2b(v * scale);
          } else if (sec == 1) {
            (qout + 8388608)[hbase + qk_off(t, hd)] = f2b(v);
          } else {
            (qout + 16777216)[hbase + v_off(t, hd)] = f2b(v);
          }
        }
      }
    }
  }
}

// ---------------------------------------------------------------------------
// 256x256 8-phase GEMM (m201 template, plain HIP): BK=64, 8 waves (2M x 4N),
// per-wave 128x64 output (acc[8][4]). LDS 128 KiB: A/B K-tiles double-buffered,
// XOR-swizzled (chunk j holds global chunk j^(row&7); reader XORs identically).
// Per K-tile: 4 phases = C-quadrants (mh,nh); each phase: ds_read frags ->
// s_barrier -> lgkmcnt(0)+sched_barrier -> setprio(1) 16xMFMA setprio(0) ->
// s_barrier. Staging for K-tile t+1 is issued in phases 0-1 of tile t
// (gld16 direct-to-LDS); the single vmcnt(0) sits at the END of phase 3,
// ~3 MFMA-phases (~1900 cyc) after issue > HBM latency, so loads stay in
// flight across 6 barriers and the drain is ~free (T3+T4). T5 = setprio.
// MODE 2: bf16 out = gelu(v)   MODE 4: fused QKV scatter (frag-order Q/K/V)
template <int MODE>
__global__ __launch_bounds__(512, 2) void gemm256(
    const u16* __restrict__ A, const u16* __restrict__ Bt,
    const float* __restrict__ b0, const float* __restrict__ b1,
    const float* __restrict__ b2, void* __restrict__ outp,
    int N, int K, int nbn, float scale) {
  __shared__ __attribute__((aligned(16))) u16 As_[2][256 * 64];
  __shared__ __attribute__((aligned(16))) u16 Bs_[2][256 * 64];
  const int tid = threadIdx.x;
  const int wid = tid >> 6, lane = tid & 63;
  const int g = lane >> 4, r = lane & 15;

  // XCD-aware bijective swizzle (grid sizes here are multiples of 8):
  // XCD k owns a contiguous chunk of (bm,bn) space, bn-fastest.
  const int nwg = gridDim.x;
  const int cpx = nwg >> 3;
  const int id2 = (blockIdx.x & 7) * cpx + (blockIdx.x >> 3);
  const int bm = id2 / nbn, bn = id2 % nbn;

  const int wrow = (wid >> 2) * 128;   // 2 M-waves
  const int wcol = (wid & 3) * 64;     // 4 N-waves

  const size_t aBase = (size_t)bm * 256 * K;
  const size_t bBase = (size_t)bn * 256 * K;
  const int ko0 = ((0 * 4 + g) ^ (r & 7)) * 8;
  const int ko1 = ((1 * 4 + g) ^ (r & 7)) * 8;

  // staging: 2048 16B-chunks per operand tile, 4 gld16/thread each.
  // LDS dest is linear in cc (gld_lds = uniform base + lane*16B); source
  // column is pre-swizzled so reads can XOR identically.
  const u16* const ab[2] = {A, Bt};
  const size_t base2[2] = {aBase, bBase};

  f32x4 acc[8][4];
  const f32x4 zero4 = {0.f, 0.f, 0.f, 0.f};
#pragma unroll
  for (int i = 0; i < 8; i++)
#pragma unroll
    for (int j = 0; j < 4; j++) acc[i][j] = zero4;

  // prologue: stage K-tile 0 into buffer 0
#pragma unroll
  for (int op = 0; op < 2; op++)
#pragma unroll
    for (int i = 0; i < 4; i++) {
      int cc = i * 512 + tid;
      int row = cc >> 3;
      int js = ((cc & 7) ^ (row & 7)) * 8;
      gld16(ab[op] + base2[op] + (size_t)row * K + js,
            (op ? (void*)&Bs_[0][cc * 8] : (void*)&As_[0][cc * 8]));
    }
  asm volatile("s_waitcnt vmcnt(0)" ::: "memory");
  __builtin_amdgcn_s_barrier();

  const int KT = K >> 6;
  int cur = 0;
  for (int t = 0; t < KT; ++t) {
    const u16* as = As_[cur];
    const u16* bs = Bs_[cur];
    const int nxt = cur ^ 1;
    const int knext = (t + 1) << 6;
    const bool more = (t + 1) < KT;
    bf16x8 af[4][2], bf[2][2];
#pragma unroll
    for (int mh = 0; mh < 2; mh++) {
#pragma unroll
      for (int nh = 0; nh < 2; nh++) {
        // --- phase (mh,nh): ds_read fragments for this C-quadrant ---
        if (nh == 0) {
#pragma unroll
          for (int mt = 0; mt < 4; mt++) {
            int arow = wrow + mh * 64 + mt * 16 + r;
            af[mt][0] = *(const bf16x8*)&as[arow * 64 + ko0];
            af[mt][1] = *(const bf16x8*)&as[arow * 64 + ko1];
          }
        }
#pragma unroll
        for (int nt = 0; nt < 2; nt++) {
          int brow = wcol + nh * 32 + nt * 16 + r;
          bf[nt][0] = *(const bf16x8*)&bs[brow * 64 + ko0];
          bf[nt][1] = *(const bf16x8*)&bs[brow * 64 + ko1];
        }
        // stage next K-tile: A-chunks in phase 0, B-chunks in phase 1
        if (mh == 0 && nh == 0 && more) {
#pragma unroll
          for (int i = 0; i < 4; i++) {
            int cc = i * 512 + tid;
            int row = cc >> 3;
            int js = ((cc & 7) ^ (row & 7)) * 8;
            gld16(A + aBase + (size_t)row * K + knext + js, &As_[nxt][cc * 8]);
          }
        }
        if (mh == 0 && nh == 1 && more) {
#pragma unroll
          for (int i = 0; i < 4; i++) {
            int cc = i * 512 + tid;
            int row = cc >> 3;
            int js = ((cc & 7) ^ (row & 7)) * 8;
            gld16(Bt + bBase + (size_t)row * K + knext + js, &Bs_[nxt][cc * 8]);
          }
        }
        __builtin_amdgcn_s_barrier();
        asm volatile("s_waitcnt lgkmcnt(0)" ::: "memory");
        __builtin_amdgcn_sched_barrier(0);
        __builtin_amdgcn_s_setprio(1);
#pragma unroll
        for (int mt = 0; mt < 4; mt++)
#pragma unroll
          for (int nt = 0; nt < 2; nt++) {
            f32x4 t0 = MFMA(af[mt][0], bf[nt][0], acc[mh * 4 + mt][nh * 2 + nt]);
            acc[mh * 4 + mt][nh * 2 + nt] = MFMA(af[mt][1], bf[nt][1], t0);
          }
        __builtin_amdgcn_s_setprio(0);
        if (mh == 1 && nh == 1 && more)
          asm volatile("s_waitcnt vmcnt(0)" ::: "memory");
        __builtin_amdgcn_s_barrier();
      }
    }
    cur = nxt;
  }

  // epilogue: C[row][col], col = r (+16*bnt), row = g*4 + rr (+16*amt)
#pragma unroll
  for (int amt = 0; amt < 8; amt++) {
#pragma unroll
    for (int bnt = 0; bnt < 4; bnt++) {
      int col = bn * 256 + wcol + bnt * 16 + r;
      float bv;
      if (MODE == 4) {
        int sec = col >> 10, hcol = col & 1023;  // sec is block-uniform
        bv = (sec == 0) ? b0[hcol] : (sec == 1) ? b1[hcol] : b2[hcol];
      } else {
        bv = b0[col];
      }
#pragma unroll
      for (int rr = 0; rr < 4; rr++) {
        int row = bm * 256 + wrow + amt * 16 + g * 4 + rr;
        float v = acc[amt][bnt][rr] + bv;
        if (MODE == 2) {
          const float c1 = -2.3025850929940457f;
          const float c2 = c1 * 0.044715f;
          float t2 = v * v;
          float z = v * (c1 + c2 * t2);
          float sg = 1.0f / (1.0f + __builtin_amdgcn_exp2f(z));
          ((u16*)outp)[(size_t)row * N + col] = f2b(v * sg);
        } else if (MODE == 4) {
          int sec = col >> 10, hcol = col & 1023;
          int head = hcol >> 6, hd = hcol & 63;
          int bb = row >> 11, tt = row & 2047;
          size_t hbase = ((size_t)bb * 16 + head) * 131072;
          u16* qout = (u16*)outp;
          if (sec == 0) {
            qout[hbase + qk_off(tt, hd)] = f2b(v * scale);
          } else if (sec == 1) {
            (qout + 8388608)[hbase + qk_off(tt, hd)] = f2b(v);
          } else {
            (qout + 16777216)[hbase + v_off(tt, hd)] = f2b(v);
          }
        }
      }
    }
  }
}

// ---------------------------------------------------------------------------
// Flash attention v4 (unchanged). Causal, Q pre-scaled by log2e/32.
__global__ __launch_bounds__(256) void attn_kernel(
    const u16* __restrict__ Q, const u16* __restrict__ Kc,
    const u16* __restrict__ Vt, const float* __restrict__ x,
    float* __restrict__ x1, u16* __restrict__ xb1) {
  const int bh = blockIdx.x & 63;
  const int slot = blockIdx.x >> 6;
  const int tid = threadIdx.x;
  const int wid = tid >> 6, lane = tid & 63;
  const int g = lane >> 4, c = lane & 15;
  const u16* Qh = Q + (size_t)bh * 131072;
  const u16* Kh = Kc + (size_t)bh * 131072;
  const u16* Vh = Vt + (size_t)bh * 131072;
  const int b = bh >> 4, head = bh & 15;

  __shared__ __attribute__((aligned(16))) u16 Ks[8192];
  __shared__ __attribute__((aligned(16))) u16 Vs[8192];
  __shared__ __attribute__((aligned(16))) u16 P[4][32][72];

  bf16x8 ones;
#pragma unroll
  for (int i = 0; i < 8; i++) ones[i] = (__bf16)1.0f;

  const f32x4 zero4 = {0.f, 0.f, 0.f, 0.f};

  for (int phase = 0; phase < 2; ++phase) {
    const int bt = phase ? (15 - slot) : slot;
    const int q0b = bt * 128;
    const int q0 = q0b + wid * 32;
    const int kendw = q0 + 32;
    const int nkt = bt + 1;

    bf16x8 qf[2][2];
#pragma unroll
    for (int mt = 0; mt < 2; mt++)
#pragma unroll
      for (int h = 0; h < 2; h++)
        qf[mt][h] = *(const bf16x8*)&Qh[(((q0 >> 4) + mt) * 2 + h) * 512 + lane * 8];

    f32x4 o[2][4];
    f32x4 lac[2];
#pragma unroll
    for (int mt = 0; mt < 2; mt++) {
      lac[mt] = zero4;
#pragma unroll
      for (int i = 0; i < 4; i++) o[mt][i] = zero4;
    }

    for (int kt = 0; kt < nkt; ++kt) {
      const int k0 = kt * 128;
#pragma unroll
      for (int r2 = 0; r2 < 4; r2++) {
        int idx = (r2 * 256 + tid) * 8;
        gld16(Kh + (size_t)k0 * 64 + idx, Ks + idx);
        gld16(Vh + (size_t)k0 * 64 + idx, Vs + idx);
      }
      __syncthreads();

#pragma unroll
      for (int s2 = 0; s2 < 2; ++s2) {
        const int k0s = k0 + s2 * 64;
        if (k0s < kendw) {
          bf16x8 kf[4][2], vf[4][2];
#pragma unroll
          for (int nt = 0; nt < 4; nt++)
#pragma unroll
            for (int h = 0; h < 2; h++) {
              kf[nt][h] = *(const bf16x8*)&Ks[s2 * 4096 + (nt * 2 + h) * 512 + lane * 8];
              vf[nt][h] = *(const bf16x8*)&Vs[s2 * 4096 + (nt * 2 + h) * 512 + lane * 8];
            }

          f32x4 sv[2][4];
#pragma unroll
          for (int mt = 0; mt < 2; mt++)
#pragma unroll
            for (int nt = 0; nt < 4; nt++) sv[mt][nt] = zero4;
#pragma unroll
          for (int nt = 0; nt < 4; nt++)
#pragma unroll
            for (int mt = 0; mt < 2; mt++) {
              sv[mt][nt] = MFMA(qf[mt][0], kf[nt][0], sv[mt][nt]);
              sv[mt][nt] = MFMA(qf[mt][1], kf[nt][1], sv[mt][nt]);
            }

          if (k0s + 64 > q0) {
#pragma unroll
            for (int mt = 0; mt < 2; mt++)
#pragma unroll
              for (int rr = 0; rr < 4; rr++) {
                int q = q0 + mt * 16 + g * 4 + rr;
#pragma unroll
                for (int nt = 0; nt < 4; nt++)
                  if (k0s + nt * 16 + c > q) sv[mt][nt][rr] = -1e30f;
              }
          }

#pragma unroll
          for (int mt = 0; mt < 2; mt++)
#pragma unroll
            for (int rr = 0; rr < 4; rr++) {
              union { u16x4 u; bf16x4 h; } pw;
#pragma unroll
              for (int nt = 0; nt < 4; nt++)
                pw.h[nt] = (__bf16)__builtin_amdgcn_exp2f(sv[mt][nt][rr]);
              *(u16x4*)&P[wid][mt * 16 + g * 4 + rr][4 * c] = pw.u;
            }

          asm volatile("s_waitcnt lgkmcnt(0)" ::: "memory");

#pragma unroll
          for (int mt = 0; mt < 2; mt++) {
            bf16x8 pf0 = *(const bf16x8*)&P[wid][mt * 16 + c][g * 8];
            bf16x8 pf1 = *(const bf16x8*)&P[wid][mt * 16 + c][32 + g * 8];
            lac[mt] = MFMA(pf0, ones, lac[mt]);
            lac[mt] = MFMA(pf1, ones, lac[mt]);
#pragma unroll
            for (int ot = 0; ot < 4; ot++) {
              f32x4 oo = MFMA(pf0, vf[ot][0], o[mt][ot]);
              o[mt][ot] = MFMA(pf1, vf[ot][1], oo);
            }
          }
        }
      }
      __syncthreads();
    }

    float inv[2][4];
#pragma unroll
    for (int mt = 0; mt < 2; mt++)
#pragma unroll
      for (int rr = 0; rr < 4; rr++) inv[mt][rr] = 1.0f / lac[mt][rr];
#pragma unroll
    for (int mt = 0; mt < 2; mt++)
#pragma unroll
      for (int ot = 0; ot < 4; ot++)
#pragma unroll
        for (int rr = 0; rr < 4; rr++) {
          int t = q0 + mt * 16 + g * 4 + rr;
          int hd = ot * 16 + c;
          size_t xi = ((size_t)b * 2048 + t) * 1024 + head * 64 + hd;
          float v = x[xi] + o[mt][ot][rr] * inv[mt][rr];
          x1[xi] = v;
          xb1[xi] = f2b(v);
        }
  }
}

// ---------------------------------------------------------------------------
extern "C" void kernel_launch(void* const* d_in, const int* in_sizes, int n_in,
                              void* d_out, int out_size, void* d_ws, size_t ws_size,
                              hipStream_t stream) {
  (void)in_sizes; (void)n_in; (void)out_size; (void)ws_size;
  const float* x = (const float*)d_in[0];
  const float* Wq = (const float*)d_in[1];
  const float* bq = (const float*)d_in[2];
  const float* Wk = (const float*)d_in[3];
  const float* bk = (const float*)d_in[4];
  const float* Wv = (const float*)d_in[5];
  const float* bv = (const float*)d_in[6];
  const float* W1 = (const float*)d_in[7];
  const float* b1 = (const float*)d_in[8];
  const float* W2 = (const float*)d_in[9];
  const float* b2 = (const float*)d_in[10];

  char* ws = (char*)d_ws;
  size_t off = 0;
  auto alloc = [&](size_t bytes) {
    char* p = ws + off;
    off += (bytes + 255) & ~(size_t)255;
    return p;
  };
  u16* xb    = (u16*)alloc(8192ull * 1024 * 2);   // bf16(x)
  u16* Wqkvt = (u16*)alloc(3072ull * 1024 * 2);   // [3072][1024] bf16 (Wq|Wk|Wv rows)
  u16* W1t   = (u16*)alloc(4096ull * 1024 * 2);
  u16* W2t   = (u16*)alloc(1024ull * 4096 * 2);
  u16* Qb    = (u16*)alloc(3ull * 8192 * 1024 * 2);  // Q|K|V frag-ordered, contiguous
  float* x1  = (float*)alloc(8192ull * 1024 * 4); // x + attn (fp32 residual)
  u16* hb    = (u16*)alloc(8192ull * 4096 * 2);   // gelu(x1@W1+b1)
  u16* xb1   = xb;  // xb dead after QKV gemm; reuse for bf16(x1)
  u16* Kb    = Qb + 8388608;
  u16* Vtb   = Qb + 16777216;

  const float qscale = 1.4426950408889634f / 32.0f;  // log2e / sqrt(H)

  // 1. x -> bf16
  xconv<<<dim3(8192), dim3(256), 0, stream>>>(x, xb, 8192 * 1024);
  // 2. all weight transposes in one launch
  wtrans_all<<<dim3(11264), dim3(32, 8), 0, stream>>>(
      Wq, Wk, Wv, W1, W2, Wqkvt, W1t, W2t);
  // 3. fused QKV projection (M=8192, N=3072, K=1024) -> frag-ordered Q/K/V
  //    256x256 8-phase: grid 32x12 = 384 blocks
  gemm256<4><<<dim3(384), dim3(512), 0, stream>>>(
      xb, Wqkvt, bq, bk, bv, Qb, 3072, 1024, 12, qscale);
  // 4. attention + residual 1  (512 blocks; paired 128-row tiles)
  attn_kernel<<<dim3(512), dim3(256), 0, stream>>>(Qb, Kb, Vtb, x, x1, xb1);
  // 5. MLP1: gelu(x1 @ W1 + b1)  (M=8192, N=4096, K=1024), 32x16 = 512 blocks
  gemm256<2><<<dim3(512), dim3(512), 0, stream>>>(
      xb1, W1t, b1, nullptr, nullptr, hb, 4096, 1024, 16, 1.0f);
  // 6. MLP2 + residual 2 -> d_out (fp32), legacy 8-wave 128x128 (N=1024 too
  //    narrow for 256-wide tiles: would leave half the CUs idle)
  gemm_bt<3, 8><<<dim3(8, 64), dim3(512), 0, stream>>>(
      hb, W2t, b2, nullptr, nullptr, d_out, x1, 1024, 4096, 1.0f);
}

// Round 2
// 432.007 us; speedup vs baseline: 1.0702x; 1.0223x over previous
//
#include <hip/hip_runtime.h>
#include <cstdint>
#include <cstddef>

// Problem constants: B=4, T=2048, H=1024, NH=16, HD=64, FF=4096, M=B*T=8192
typedef unsigned short u16;
typedef __attribute__((ext_vector_type(8))) __bf16 bf16x8;
typedef __attribute__((ext_vector_type(4))) __bf16 bf16x4;
typedef __attribute__((ext_vector_type(4))) float f32x4;
typedef __attribute__((ext_vector_type(4))) u16 u16x4;

#define MFMA(a, b, c) __builtin_amdgcn_mfma_f32_16x16x32_bf16((a), (b), (c), 0, 0, 0)

__device__ __forceinline__ u16 f2b(float f) {  // native RNE cvt (1-2 ops)
  union { __bf16 h; u16 u; } v;
  v.h = (__bf16)f;
  return v.u;
}

__device__ __forceinline__ void gld16(const void* g, void* l) {
  __builtin_amdgcn_global_load_lds(
      (__attribute__((address_space(1))) void*)(void*)(g),
      (__attribute__((address_space(3))) void*)(l), 16, 0, 0);
}

// Fragment-ordered layouts (per head, 131072 u16 = 2048x64):
// Q/K: element (t, hd): chunk ((t>>4)*2 + (hd>>5)), lane ((hd>>3)&3)*16 + (t&15),
//      byte-slot hd&7. MFMA lane l reads its 16B at chunk_base + l*16B.
__device__ __forceinline__ size_t qk_off(int t, int hd) {
  return (size_t)((((t >> 4) * 2 + (hd >> 5)) * 512)
                  + ((((hd >> 3) & 3) * 16 + (t & 15)) * 8) + (hd & 7));
}
// V: keys kk-permuted within 64-groups (kk = (t&15)*4 + ((t>>4)&3)) to match the
//    P-tile LDS packing; fragment order for PV B-operand reads.
__device__ __forceinline__ size_t v_off(int t, int hd) {
  int kk = ((t & 15) << 2) | ((t >> 4) & 3);
  return (size_t)(((t >> 6) * 4096)
                  + (((hd >> 4) * 2 + (kk >> 5)) * 512)
                  + ((((kk >> 3) & 3) * 16 + (hd & 15)) * 8) + (kk & 7));
}

// ---------------------------------------------------------------------------
// elementwise fp32 -> bf16 (vectorized x4)
__global__ void xconv(const float* __restrict__ in, u16* __restrict__ out, int n) {
  int i = (blockIdx.x * blockDim.x + threadIdx.x) * 4;
  if (i >= n) return;
  float4 v = *(const float4*)(in + i);
  u16x4 o;
  o[0] = f2b(v.x); o[1] = f2b(v.y); o[2] = f2b(v.z); o[3] = f2b(v.w);
  *(u16x4*)(out + i) = o;
}

// ---------------------------------------------------------------------------
// All weight transposes in ONE launch. W [K,N] fp32 -> Wt [N,K] bf16.
__global__ void wtrans_all(const float* __restrict__ Wq, const float* __restrict__ Wk,
                           const float* __restrict__ Wv, const float* __restrict__ W1,
                           const float* __restrict__ W2, u16* __restrict__ Wqkvt,
                           u16* __restrict__ W1t, u16* __restrict__ W2t) {
  __shared__ float tile[32][33];
  int blk = blockIdx.x;
  const float* W;
  u16* Wt;
  int Kd, Nd, nx;
  if (blk < 3072) {
    int s = blk >> 10;
    blk &= 1023;
    W = (s == 0) ? Wq : (s == 1) ? Wk : Wv;
    Wt = Wqkvt + (size_t)s * 1048576;
    Kd = 1024; Nd = 1024; nx = 32;
  } else if (blk < 7168) {
    blk -= 3072; W = W1; Wt = W1t; Kd = 1024; Nd = 4096; nx = 128;
  } else {
    blk -= 7168; W = W2; Wt = W2t; Kd = 4096; Nd = 1024; nx = 32;
  }
  int n0 = (blk % nx) * 32, k0 = (blk / nx) * 32;
  int tx = threadIdx.x, ty = threadIdx.y;
#pragma unroll
  for (int i = 0; i < 4; i++)
    tile[ty + i * 8][tx] = W[(size_t)(k0 + ty + i * 8) * Nd + n0 + tx];
  __syncthreads();
#pragma unroll
  for (int i = 0; i < 4; i++)
    Wt[(size_t)(n0 + ty + i * 8) * Kd + k0 + tx] = f2b(tile[tx][ty + i * 8]);
}

// ---------------------------------------------------------------------------
// 256x128 3-buffer counted-vmcnt GEMM. BK=64, 8 waves as 4M x 2N (64x64/wave,
// acc[4][4]). LDS 144 KiB = 3 x (A 32K + B 16K): while computing tile t from
// buf[t%3], stage tile t+2 into buf[(t+2)%3] (A in phase 0, B in phase 1).
// End-of-tile wait = vmcnt(6): the 6 loads/thread for tile t+2 may stay in
// flight; the oldest 6 (tile t+1, issued a full tile earlier) are guaranteed
// landed. Never drains mid-loop (T3+T4). 2 phases/tile (k-halves), each:
// 8x ds_read_b128 -> barrier -> lgkmcnt(0)+sched_barrier -> setprio(1)
// 16x MFMA setprio(0) -> barrier (T5). XOR-swizzled LDS both sides.
// XCD mapping: XCD x owns bm in [4x,4x+4) x all bn, walked in 8-wide bn
// chunks -> concurrent 32 blocks/XCD = 4bm x 8bn window = 2MB A + 2MB B
// working set = fits the 4MB XCD L2 (A panels stay L2-hot all dispatch).
// Requires M = 8192 (nbm = 32), nbn % 8 == 0.
// MODE 2: bf16 out = gelu(v)   MODE 3: fp32 out = v + resid
// MODE 4: fused QKV scatter (frag-order Q/K/V)
template <int MODE>
__global__ __launch_bounds__(512, 2) void gemm256(
    const u16* __restrict__ A, const u16* __restrict__ Bt,
    const float* __restrict__ b0, const float* __restrict__ b1,
    const float* __restrict__ b2, void* __restrict__ outp,
    const float* __restrict__ resid, int N, int K, float scale) {
  __shared__ __attribute__((aligned(16))) u16 As_[3][16384];
  __shared__ __attribute__((aligned(16))) u16 Bs_[3][8192];
  const int tid = threadIdx.x;
  const int wid = tid >> 6, lane = tid & 63;
  const int g = lane >> 4, r = lane & 15;

  // XCD-aware 2-D mapping (bijective for grid = 32 * nbn, nbn % 8 == 0)
  const int xcd = blockIdx.x & 7;
  const int ii = blockIdx.x >> 3;
  const int bm = xcd * 4 + ((ii & 31) >> 3);
  const int bn = (ii >> 5) * 8 + (ii & 7);

  const int wrow = (wid >> 1) * 64;   // 4 M-waves
  const int wcol = (wid & 1) * 64;    // 2 N-waves

  const int ko0 = ((0 * 4 + g) ^ (r & 7)) * 8;
  const int ko1 = ((1 * 4 + g) ^ (r & 7)) * 8;

  // per-thread staging source offsets (u16 elements); add t*64 per K-tile.
  // LDS chunk cc = row*8 + j holds global k-chunk j^(row&7) (XOR swizzle).
  size_t aOff[4], bOff[2];
#pragma unroll
  for (int i4 = 0; i4 < 4; i4++) {
    int cc = i4 * 512 + tid, row = cc >> 3;
    int js = ((cc & 7) ^ (row & 7)) * 8;
    aOff[i4] = (size_t)(bm * 256 + row) * K + js;
  }
#pragma unroll
  for (int i2 = 0; i2 < 2; i2++) {
    int cc = i2 * 512 + tid, row = cc >> 3;
    int js = ((cc & 7) ^ (row & 7)) * 8;
    bOff[i2] = (size_t)(bn * 128 + row) * K + js;
  }

  f32x4 acc[4][4];
  const f32x4 zero4 = {0.f, 0.f, 0.f, 0.f};
#pragma unroll
  for (int i = 0; i < 4; i++)
#pragma unroll
    for (int j = 0; j < 4; j++) acc[i][j] = zero4;

  // prologue: stage tiles 0 and 1; wait for tile 0 only (tile 1 in flight)
#pragma unroll
  for (int i4 = 0; i4 < 4; i4++) gld16(A + aOff[i4], &As_[0][(i4 * 512 + tid) * 8]);
#pragma unroll
  for (int i2 = 0; i2 < 2; i2++) gld16(Bt + bOff[i2], &Bs_[0][(i2 * 512 + tid) * 8]);
#pragma unroll
  for (int i4 = 0; i4 < 4; i4++) gld16(A + aOff[i4] + 64, &As_[1][(i4 * 512 + tid) * 8]);
#pragma unroll
  for (int i2 = 0; i2 < 2; i2++) gld16(Bt + bOff[i2] + 64, &Bs_[1][(i2 * 512 + tid) * 8]);
  asm volatile("s_waitcnt vmcnt(6)" ::: "memory");
  __builtin_amdgcn_s_barrier();

  const int KT = K >> 6;
  int cur = 0;
  for (int t = 0; t < KT; ++t) {
    const u16* as = As_[cur];
    const u16* bs = Bs_[cur];
    const int stg = (cur == 0) ? 2 : cur - 1;  // (t+2)%3
    const bool more = (t + 2) < KT;
    const size_t k2 = (size_t)(t + 2) * 64;
    bf16x8 af[4], bf[4];

    // ---- phase 0 (k-half 0): ds_read + stage A(t+2) ----
#pragma unroll
    for (int mt = 0; mt < 4; mt++)
      af[mt] = *(const bf16x8*)&as[(wrow + mt * 16 + r) * 64 + ko0];
#pragma unroll
    for (int nt = 0; nt < 4; nt++)
      bf[nt] = *(const bf16x8*)&bs[(wcol + nt * 16 + r) * 64 + ko0];
    if (more) {
#pragma unroll
      for (int i4 = 0; i4 < 4; i4++)
        gld16(A + aOff[i4] + k2, &As_[stg][(i4 * 512 + tid) * 8]);
    }
    __builtin_amdgcn_s_barrier();
    asm volatile("s_waitcnt lgkmcnt(0)" ::: "memory");
    __builtin_amdgcn_sched_barrier(0);
    __builtin_amdgcn_s_setprio(1);
#pragma unroll
    for (int mt = 0; mt < 4; mt++)
#pragma unroll
      for (int nt = 0; nt < 4; nt++)
        acc[mt][nt] = MFMA(af[mt], bf[nt], acc[mt][nt]);
    __builtin_amdgcn_s_setprio(0);
    __builtin_amdgcn_s_barrier();

    // ---- phase 1 (k-half 1): ds_read + stage B(t+2) ----
#pragma unroll
    for (int mt = 0; mt < 4; mt++)
      af[mt] = *(const bf16x8*)&as[(wrow + mt * 16 + r) * 64 + ko1];
#pragma unroll
    for (int nt = 0; nt < 4; nt++)
      bf[nt] = *(const bf16x8*)&bs[(wcol + nt * 16 + r) * 64 + ko1];
    if (more) {
#pragma unroll
      for (int i2 = 0; i2 < 2; i2++)
        gld16(Bt + bOff[i2] + k2, &Bs_[stg][(i2 * 512 + tid) * 8]);
    }
    __builtin_amdgcn_s_barrier();
    asm volatile("s_waitcnt lgkmcnt(0)" ::: "memory");
    __builtin_amdgcn_sched_barrier(0);
    __builtin_amdgcn_s_setprio(1);
#pragma unroll
    for (int mt = 0; mt < 4; mt++)
#pragma unroll
      for (int nt = 0; nt < 4; nt++)
        acc[mt][nt] = MFMA(af[mt], bf[nt], acc[mt][nt]);
    __builtin_amdgcn_s_setprio(0);
    // counted wait: tile t+1 (issued during tile t-1) guaranteed landed;
    // tile t+2's 6 loads stay in flight across the barrier.
    if (t + 1 < KT) {
      if (more) asm volatile("s_waitcnt vmcnt(6)" ::: "memory");
      else      asm volatile("s_waitcnt vmcnt(0)" ::: "memory");
    }
    __builtin_amdgcn_s_barrier();
    cur = (cur == 2) ? 0 : cur + 1;
  }

  // epilogue: C[row][col], col = r (+16*nt), row = g*4 + q (+16*mt)
#pragma unroll
  for (int mt = 0; mt < 4; mt++) {
#pragma unroll
    for (int nt = 0; nt < 4; nt++) {
      int col = bn * 128 + wcol + nt * 16 + r;
      float bv;
      if (MODE == 4) {
        int sec = col >> 10, hcol = col & 1023;  // sec is block-uniform
        bv = (sec == 0) ? b0[hcol] : (sec == 1) ? b1[hcol] : b2[hcol];
      } else {
        bv = b0[col];
      }
#pragma unroll
      for (int q = 0; q < 4; q++) {
        int row = bm * 256 + wrow + mt * 16 + g * 4 + q;
        float v = acc[mt][nt][q] + bv;
        if (MODE == 2) {
          const float c1 = -2.3025850929940457f;
          const float c2 = c1 * 0.044715f;
          float t2 = v * v;
          float z = v * (c1 + c2 * t2);
          float sg = 1.0f / (1.0f + __builtin_amdgcn_exp2f(z));
          ((u16*)outp)[(size_t)row * N + col] = f2b(v * sg);
        } else if (MODE == 3) {
          ((float*)outp)[(size_t)row * N + col] = v + resid[(size_t)row * N + col];
        } else if (MODE == 4) {
          int sec = col >> 10, hcol = col & 1023;
          int head = hcol >> 6, hd = hcol & 63;
          int bb = row >> 11, tt = row & 2047;
          size_t hbase = ((size_t)bb * 16 + head) * 131072;
          u16* qout = (u16*)outp;
          if (sec == 0) {
            qout[hbase + qk_off(tt, hd)] = f2b(v * scale);
          } else if (sec == 1) {
            (qout + 8388608)[hbase + qk_off(tt, hd)] = f2b(v);
          } else {
            (qout + 16777216)[hbase + v_off(tt, hd)] = f2b(v);
          }
        }
      }
    }
  }
}

// ---------------------------------------------------------------------------
// Flash attention v4 (unchanged). Causal, Q pre-scaled by log2e/32.
__global__ __launch_bounds__(256) void attn_kernel(
    const u16* __restrict__ Q, const u16* __restrict__ Kc,
    const u16* __restrict__ Vt, const float* __restrict__ x,
    float* __restrict__ x1, u16* __restrict__ xb1) {
  const int bh = blockIdx.x & 63;
  const int slot = blockIdx.x >> 6;
  const int tid = threadIdx.x;
  const int wid = tid >> 6, lane = tid & 63;
  const int g = lane >> 4, c = lane & 15;
  const u16* Qh = Q + (size_t)bh * 131072;
  const u16* Kh = Kc + (size_t)bh * 131072;
  const u16* Vh = Vt + (size_t)bh * 131072;
  const int b = bh >> 4, head = bh & 15;

  __shared__ __attribute__((aligned(16))) u16 Ks[8192];
  __shared__ __attribute__((aligned(16))) u16 Vs[8192];
  __shared__ __attribute__((aligned(16))) u16 P[4][32][72];

  bf16x8 ones;
#pragma unroll
  for (int i = 0; i < 8; i++) ones[i] = (__bf16)1.0f;

  const f32x4 zero4 = {0.f, 0.f, 0.f, 0.f};

  for (int phase = 0; phase < 2; ++phase) {
    const int bt = phase ? (15 - slot) : slot;
    const int q0b = bt * 128;
    const int q0 = q0b + wid * 32;
    const int kendw = q0 + 32;
    const int nkt = bt + 1;

    bf16x8 qf[2][2];
#pragma unroll
    for (int mt = 0; mt < 2; mt++)
#pragma unroll
      for (int h = 0; h < 2; h++)
        qf[mt][h] = *(const bf16x8*)&Qh[(((q0 >> 4) + mt) * 2 + h) * 512 + lane * 8];

    f32x4 o[2][4];
    f32x4 lac[2];
#pragma unroll
    for (int mt = 0; mt < 2; mt++) {
      lac[mt] = zero4;
#pragma unroll
      for (int i = 0; i < 4; i++) o[mt][i] = zero4;
    }

    for (int kt = 0; kt < nkt; ++kt) {
      const int k0 = kt * 128;
#pragma unroll
      for (int r2 = 0; r2 < 4; r2++) {
        int idx = (r2 * 256 + tid) * 8;
        gld16(Kh + (size_t)k0 * 64 + idx, Ks + idx);
        gld16(Vh + (size_t)k0 * 64 + idx, Vs + idx);
      }
      __syncthreads();

#pragma unroll
      for (int s2 = 0; s2 < 2; ++s2) {
        const int k0s = k0 + s2 * 64;
        if (k0s < kendw) {
          bf16x8 kf[4][2], vf[4][2];
#pragma unroll
          for (int nt = 0; nt < 4; nt++)
#pragma unroll
            for (int h = 0; h < 2; h++) {
              kf[nt][h] = *(const bf16x8*)&Ks[s2 * 4096 + (nt * 2 + h) * 512 + lane * 8];
              vf[nt][h] = *(const bf16x8*)&Vs[s2 * 4096 + (nt * 2 + h) * 512 + lane * 8];
            }

          f32x4 sv[2][4];
#pragma unroll
          for (int mt = 0; mt < 2; mt++)
#pragma unroll
            for (int nt = 0; nt < 4; nt++) sv[mt][nt] = zero4;
#pragma unroll
          for (int nt = 0; nt < 4; nt++)
#pragma unroll
            for (int mt = 0; mt < 2; mt++) {
              sv[mt][nt] = MFMA(qf[mt][0], kf[nt][0], sv[mt][nt]);
              sv[mt][nt] = MFMA(qf[mt][1], kf[nt][1], sv[mt][nt]);
            }

          if (k0s + 64 > q0) {
#pragma unroll
            for (int mt = 0; mt < 2; mt++)
#pragma unroll
              for (int rr = 0; rr < 4; rr++) {
                int q = q0 + mt * 16 + g * 4 + rr;
#pragma unroll
                for (int nt = 0; nt < 4; nt++)
                  if (k0s + nt * 16 + c > q) sv[mt][nt][rr] = -1e30f;
              }
          }

#pragma unroll
          for (int mt = 0; mt < 2; mt++)
#pragma unroll
            for (int rr = 0; rr < 4; rr++) {
              union { u16x4 u; bf16x4 h; } pw;
#pragma unroll
              for (int nt = 0; nt < 4; nt++)
                pw.h[nt] = (__bf16)__builtin_amdgcn_exp2f(sv[mt][nt][rr]);
              *(u16x4*)&P[wid][mt * 16 + g * 4 + rr][4 * c] = pw.u;
            }

          asm volatile("s_waitcnt lgkmcnt(0)" ::: "memory");

#pragma unroll
          for (int mt = 0; mt < 2; mt++) {
            bf16x8 pf0 = *(const bf16x8*)&P[wid][mt * 16 + c][g * 8];
            bf16x8 pf1 = *(const bf16x8*)&P[wid][mt * 16 + c][32 + g * 8];
            lac[mt] = MFMA(pf0, ones, lac[mt]);
            lac[mt] = MFMA(pf1, ones, lac[mt]);
#pragma unroll
            for (int ot = 0; ot < 4; ot++) {
              f32x4 oo = MFMA(pf0, vf[ot][0], o[mt][ot]);
              o[mt][ot] = MFMA(pf1, vf[ot][1], oo);
            }
          }
        }
      }
      __syncthreads();
    }

    float inv[2][4];
#pragma unroll
    for (int mt = 0; mt < 2; mt++)
#pragma unroll
      for (int rr = 0; rr < 4; rr++) inv[mt][rr] = 1.0f / lac[mt][rr];
#pragma unroll
    for (int mt = 0; mt < 2; mt++)
#pragma unroll
      for (int ot = 0; ot < 4; ot++)
#pragma unroll
        for (int rr = 0; rr < 4; rr++) {
          int t = q0 + mt * 16 + g * 4 + rr;
          int hd = ot * 16 + c;
          size_t xi = ((size_t)b * 2048 + t) * 1024 + head * 64 + hd;
          float v = x[xi] + o[mt][ot][rr] * inv[mt][rr];
          x1[xi] = v;
          xb1[xi] = f2b(v);
        }
  }
}

// ---------------------------------------------------------------------------
extern "C" void kernel_launch(void* const* d_in, const int* in_sizes, int n_in,
                              void* d_out, int out_size, void* d_ws, size_t ws_size,
                              hipStream_t stream) {
  (void)in_sizes; (void)n_in; (void)out_size; (void)ws_size;
  const float* x = (const float*)d_in[0];
  const float* Wq = (const float*)d_in[1];
  const float* bq = (const float*)d_in[2];
  const float* Wk = (const float*)d_in[3];
  const float* bk = (const float*)d_in[4];
  const float* Wv = (const float*)d_in[5];
  const float* bv = (const float*)d_in[6];
  const float* W1 = (const float*)d_in[7];
  const float* b1 = (const float*)d_in[8];
  const float* W2 = (const float*)d_in[9];
  const float* b2 = (const float*)d_in[10];

  char* ws = (char*)d_ws;
  size_t off = 0;
  auto alloc = [&](size_t bytes) {
    char* p = ws + off;
    off += (bytes + 255) & ~(size_t)255;
    return p;
  };
  u16* xb    = (u16*)alloc(8192ull * 1024 * 2);   // bf16(x)
  u16* Wqkvt = (u16*)alloc(3072ull * 1024 * 2);   // [3072][1024] bf16 (Wq|Wk|Wv rows)
  u16* W1t   = (u16*)alloc(4096ull * 1024 * 2);
  u16* W2t   = (u16*)alloc(1024ull * 4096 * 2);
  u16* Qb    = (u16*)alloc(3ull * 8192 * 1024 * 2);  // Q|K|V frag-ordered, contiguous
  float* x1  = (float*)alloc(8192ull * 1024 * 4); // x + attn (fp32 residual)
  u16* hb    = (u16*)alloc(8192ull * 4096 * 2);   // gelu(x1@W1+b1)
  u16* xb1   = xb;  // xb dead after QKV gemm; reuse for bf16(x1)
  u16* Kb    = Qb + 8388608;
  u16* Vtb   = Qb + 16777216;

  const float qscale = 1.4426950408889634f / 32.0f;  // log2e / sqrt(H)

  // 1. x -> bf16
  xconv<<<dim3(8192), dim3(256), 0, stream>>>(x, xb, 8192 * 1024);
  // 2. all weight transposes in one launch
  wtrans_all<<<dim3(11264), dim3(32, 8), 0, stream>>>(
      Wq, Wk, Wv, W1, W2, Wqkvt, W1t, W2t);
  // 3. fused QKV projection (M=8192, N=3072, K=1024) -> frag-ordered Q/K/V
  //    256x128 tiles: 32 x 24 = 768 blocks
  gemm256<4><<<dim3(768), dim3(512), 0, stream>>>(
      xb, Wqkvt, bq, bk, bv, Qb, nullptr, 3072, 1024, qscale);
  // 4. attention + residual 1  (512 blocks; paired 128-row tiles)
  attn_kernel<<<dim3(512), dim3(256), 0, stream>>>(Qb, Kb, Vtb, x, x1, xb1);
  // 5. MLP1: gelu(x1 @ W1 + b1)  (M=8192, N=4096, K=1024): 32 x 32 = 1024 blocks
  gemm256<2><<<dim3(1024), dim3(512), 0, stream>>>(
      xb1, W1t, b1, nullptr, nullptr, hb, nullptr, 4096, 1024, 1.0f);
  // 6. MLP2 + residual 2 -> d_out (fp32) (M=8192, N=1024, K=4096): 32 x 8 = 256
  //    blocks = exactly 1 block/CU, one clean round, 64 K-tiles of pipeline.
  gemm256<3><<<dim3(256), dim3(512), 0, stream>>>(
      hb, W2t, b2, nullptr, nullptr, d_out, x1, 1024, 4096, 1.0f);
}

// Round 3
// 429.262 us; speedup vs baseline: 1.0770x; 1.0064x over previous
//
#include <hip/hip_runtime.h>
#include <cstdint>
#include <cstddef>

// Problem constants: B=4, T=2048, H=1024, NH=16, HD=64, FF=4096, M=B*T=8192
typedef unsigned short u16;
typedef __attribute__((ext_vector_type(8))) __bf16 bf16x8;
typedef __attribute__((ext_vector_type(4))) __bf16 bf16x4;
typedef __attribute__((ext_vector_type(4))) float f32x4;
typedef __attribute__((ext_vector_type(4))) u16 u16x4;

#define MFMA(a, b, c) __builtin_amdgcn_mfma_f32_16x16x32_bf16((a), (b), (c), 0, 0, 0)

__device__ __forceinline__ u16 f2b(float f) {  // native RNE cvt (1-2 ops)
  union { __bf16 h; u16 u; } v;
  v.h = (__bf16)f;
  return v.u;
}

__device__ __forceinline__ void gld16(const void* g, void* l) {
  __builtin_amdgcn_global_load_lds(
      (__attribute__((address_space(1))) void*)(void*)(g),
      (__attribute__((address_space(3))) void*)(l), 16, 0, 0);
}

// Fragment-ordered layouts (per head, 131072 u16 = 2048x64):
// Q/K: element (t, hd): chunk ((t>>4)*2 + (hd>>5)), lane ((hd>>3)&3)*16 + (t&15),
//      byte-slot hd&7. MFMA lane l reads its 16B at chunk_base + l*16B.
__device__ __forceinline__ size_t qk_off(int t, int hd) {
  return (size_t)((((t >> 4) * 2 + (hd >> 5)) * 512)
                  + ((((hd >> 3) & 3) * 16 + (t & 15)) * 8) + (hd & 7));
}
// V: keys kk-permuted within 64-groups (kk = (t&15)*4 + ((t>>4)&3)) to match the
//    P-tile LDS packing; fragment order for PV B-operand reads.
__device__ __forceinline__ size_t v_off(int t, int hd) {
  int kk = ((t & 15) << 2) | ((t >> 4) & 3);
  return (size_t)(((t >> 6) * 4096)
                  + (((hd >> 4) * 2 + (kk >> 5)) * 512)
                  + ((((kk >> 3) & 3) * 16 + (hd & 15)) * 8) + (kk & 7));
}

// ---------------------------------------------------------------------------
// elementwise fp32 -> bf16 (vectorized x4)
__global__ void xconv(const float* __restrict__ in, u16* __restrict__ out, int n) {
  int i = (blockIdx.x * blockDim.x + threadIdx.x) * 4;
  if (i >= n) return;
  float4 v = *(const float4*)(in + i);
  u16x4 o;
  o[0] = f2b(v.x); o[1] = f2b(v.y); o[2] = f2b(v.z); o[3] = f2b(v.w);
  *(u16x4*)(out + i) = o;
}

// ---------------------------------------------------------------------------
// All weight transposes in ONE launch. W [K,N] fp32 -> Wt [N,K] bf16.
__global__ void wtrans_all(const float* __restrict__ Wq, const float* __restrict__ Wk,
                           const float* __restrict__ Wv, const float* __restrict__ W1,
                           const float* __restrict__ W2, u16* __restrict__ Wqkvt,
                           u16* __restrict__ W1t, u16* __restrict__ W2t) {
  __shared__ float tile[32][33];
  int blk = blockIdx.x;
  const float* W;
  u16* Wt;
  int Kd, Nd, nx;
  if (blk < 3072) {
    int s = blk >> 10;
    blk &= 1023;
    W = (s == 0) ? Wq : (s == 1) ? Wk : Wv;
    Wt = Wqkvt + (size_t)s * 1048576;
    Kd = 1024; Nd = 1024; nx = 32;
  } else if (blk < 7168) {
    blk -= 3072; W = W1; Wt = W1t; Kd = 1024; Nd = 4096; nx = 128;
  } else {
    blk -= 7168; W = W2; Wt = W2t; Kd = 4096; Nd = 1024; nx = 32;
  }
  int n0 = (blk % nx) * 32, k0 = (blk / nx) * 32;
  int tx = threadIdx.x, ty = threadIdx.y;
#pragma unroll
  for (int i = 0; i < 4; i++)
    tile[ty + i * 8][tx] = W[(size_t)(k0 + ty + i * 8) * Nd + n0 + tx];
  __syncthreads();
#pragma unroll
  for (int i = 0; i < 4; i++)
    Wt[(size_t)(n0 + ty + i * 8) * Kd + k0 + tx] = f2b(tile[tx][ty + i * 8]);
}

// ---------------------------------------------------------------------------
// 256x128 3-buffer counted-vmcnt GEMM, barrier-light K-loop. BK=64, 8 waves
// as 4M x 2N (64x64/wave, acc[4][4]). LDS 144 KiB = 3 x (A 32K + B 16K).
// Per K-tile (NO intra-tile barriers -- both k-halves read the stable buffer
// `cur`, so the only hazard is staging-overwrite, covered by the end-of-tile
// barrier since every wave's ds_reads complete before its last MFMA issues):
//   16x ds_read_b128 (halves 0+1) -> 6x gld16 stage tile t+2 -> 32 MFMA
//   (compiler interleaves via fine-grained lgkmcnt; LDS port and matrix pipe
//   overlap instead of alternating) -> vmcnt(6) counted -> s_barrier.
// vmcnt(6): tile t+2's 6 loads stay in flight; tile t+1's (issued a full tile
// ago) are guaranteed landed. Never drains mid-loop (T3+T4).
// XOR-swizzled LDS both sides (conflict-free ds_read_b128, measured 0).
// XCD mapping: XCD x owns bm in [4x,4x+4) x all bn in 8-wide chunks ->
// concurrent 32 blocks/XCD (1 block/CU) = 4bm x 8bn window = 2MB A + 2MB B
// = fits the 4MB XCD L2 for K=1024 shapes. Requires M=8192, nbn % 8 == 0.
// MODE 2: bf16 out = gelu(v)   MODE 3: fp32 out = v + resid
// MODE 4: fused QKV scatter (frag-order Q/K/V)
template <int MODE>
__global__ __launch_bounds__(512, 2) void gemm256(
    const u16* __restrict__ A, const u16* __restrict__ Bt,
    const float* __restrict__ b0, const float* __restrict__ b1,
    const float* __restrict__ b2, void* __restrict__ outp,
    const float* __restrict__ resid, int N, int K, float scale) {
  __shared__ __attribute__((aligned(16))) u16 As_[3][16384];
  __shared__ __attribute__((aligned(16))) u16 Bs_[3][8192];
  const int tid = threadIdx.x;
  const int wid = tid >> 6, lane = tid & 63;
  const int g = lane >> 4, r = lane & 15;

  // XCD-aware 2-D mapping (bijective for grid = 32 * nbn, nbn % 8 == 0)
  const int xcd = blockIdx.x & 7;
  const int ii = blockIdx.x >> 3;
  const int bm = xcd * 4 + ((ii & 31) >> 3);
  const int bn = (ii >> 5) * 8 + (ii & 7);

  const int wrow = (wid >> 1) * 64;   // 4 M-waves
  const int wcol = (wid & 1) * 64;    // 2 N-waves

  const int ko0 = ((0 * 4 + g) ^ (r & 7)) * 8;
  const int ko1 = ((1 * 4 + g) ^ (r & 7)) * 8;

  // per-thread staging source offsets (u16 elements); add t*64 per K-tile.
  // LDS chunk cc = row*8 + j holds global k-chunk j^(row&7) (XOR swizzle).
  size_t aOff[4], bOff[2];
#pragma unroll
  for (int i4 = 0; i4 < 4; i4++) {
    int cc = i4 * 512 + tid, row = cc >> 3;
    int js = ((cc & 7) ^ (row & 7)) * 8;
    aOff[i4] = (size_t)(bm * 256 + row) * K + js;
  }
#pragma unroll
  for (int i2 = 0; i2 < 2; i2++) {
    int cc = i2 * 512 + tid, row = cc >> 3;
    int js = ((cc & 7) ^ (row & 7)) * 8;
    bOff[i2] = (size_t)(bn * 128 + row) * K + js;
  }

  f32x4 acc[4][4];
  const f32x4 zero4 = {0.f, 0.f, 0.f, 0.f};
#pragma unroll
  for (int i = 0; i < 4; i++)
#pragma unroll
    for (int j = 0; j < 4; j++) acc[i][j] = zero4;

  // prologue: stage tiles 0 and 1; wait for tile 0 only (tile 1 in flight)
#pragma unroll
  for (int i4 = 0; i4 < 4; i4++) gld16(A + aOff[i4], &As_[0][(i4 * 512 + tid) * 8]);
#pragma unroll
  for (int i2 = 0; i2 < 2; i2++) gld16(Bt + bOff[i2], &Bs_[0][(i2 * 512 + tid) * 8]);
#pragma unroll
  for (int i4 = 0; i4 < 4; i4++) gld16(A + aOff[i4] + 64, &As_[1][(i4 * 512 + tid) * 8]);
#pragma unroll
  for (int i2 = 0; i2 < 2; i2++) gld16(Bt + bOff[i2] + 64, &Bs_[1][(i2 * 512 + tid) * 8]);
  asm volatile("s_waitcnt vmcnt(6)" ::: "memory");
  __builtin_amdgcn_s_barrier();

  const int KT = K >> 6;
  int cur = 0;
  for (int t = 0; t < KT; ++t) {
    const u16* as = As_[cur];
    const u16* bs = Bs_[cur];
    const int stg = (cur == 0) ? 2 : cur - 1;  // (t+2)%3
    const bool more = (t + 2) < KT;
    const size_t k2 = (size_t)(t + 2) * 64;

    // fragment reads for BOTH k-halves (16 x ds_read_b128, buffer `cur`)
    bf16x8 af0[4], bf0[4], af1[4], bf1[4];
#pragma unroll
    for (int mt = 0; mt < 4; mt++) {
      af0[mt] = *(const bf16x8*)&as[(wrow + mt * 16 + r) * 64 + ko0];
      af1[mt] = *(const bf16x8*)&as[(wrow + mt * 16 + r) * 64 + ko1];
    }
#pragma unroll
    for (int nt = 0; nt < 4; nt++) {
      bf0[nt] = *(const bf16x8*)&bs[(wcol + nt * 16 + r) * 64 + ko0];
      bf1[nt] = *(const bf16x8*)&bs[(wcol + nt * 16 + r) * 64 + ko1];
    }

    // stage tile t+2 into buf stg (lands before it's read: gated by the
    // vmcnt(6) at the end of tile t+1 plus that tile's barrier)
    if (more) {
#pragma unroll
      for (int i4 = 0; i4 < 4; i4++)
        gld16(A + aOff[i4] + k2, &As_[stg][(i4 * 512 + tid) * 8]);
#pragma unroll
      for (int i2 = 0; i2 < 2; i2++)
        gld16(Bt + bOff[i2] + k2, &Bs_[stg][(i2 * 512 + tid) * 8]);
    }

    // 32 MFMA; compiler interleaves with counted lgkmcnt so half-0 compute
    // runs while half-1 reads drain on the LDS port.
#pragma unroll
    for (int mt = 0; mt < 4; mt++)
#pragma unroll
      for (int nt = 0; nt < 4; nt++)
        acc[mt][nt] = MFMA(af0[mt], bf0[nt], acc[mt][nt]);
#pragma unroll
    for (int mt = 0; mt < 4; mt++)
#pragma unroll
      for (int nt = 0; nt < 4; nt++)
        acc[mt][nt] = MFMA(af1[mt], bf1[nt], acc[mt][nt]);

    // counted wait: tile t+1 (issued during tile t-1) guaranteed landed;
    // tile t+2's 6 loads stay in flight across the barrier.
    if (t + 1 < KT) {
      if (more) asm volatile("s_waitcnt vmcnt(6)" ::: "memory");
      else      asm volatile("s_waitcnt vmcnt(0)" ::: "memory");
    }
    __builtin_amdgcn_s_barrier();
    cur = (cur == 2) ? 0 : cur + 1;
  }

  // epilogue: C[row][col], col = r (+16*nt), row = g*4 + q (+16*mt)
#pragma unroll
  for (int mt = 0; mt < 4; mt++) {
#pragma unroll
    for (int nt = 0; nt < 4; nt++) {
      int col = bn * 128 + wcol + nt * 16 + r;
      float bv;
      if (MODE == 4) {
        int sec = col >> 10, hcol = col & 1023;  // sec is block-uniform
        bv = (sec == 0) ? b0[hcol] : (sec == 1) ? b1[hcol] : b2[hcol];
      } else {
        bv = b0[col];
      }
#pragma unroll
      for (int q = 0; q < 4; q++) {
        int row = bm * 256 + wrow + mt * 16 + g * 4 + q;
        float v = acc[mt][nt][q] + bv;
        if (MODE == 2) {
          const float c1 = -2.3025850929940457f;
          const float c2 = c1 * 0.044715f;
          float t2 = v * v;
          float z = v * (c1 + c2 * t2);
          float sg = 1.0f / (1.0f + __builtin_amdgcn_exp2f(z));
          ((u16*)outp)[(size_t)row * N + col] = f2b(v * sg);
        } else if (MODE == 3) {
          ((float*)outp)[(size_t)row * N + col] = v + resid[(size_t)row * N + col];
        } else if (MODE == 4) {
          int sec = col >> 10, hcol = col & 1023;
          int head = hcol >> 6, hd = hcol & 63;
          int bb = row >> 11, tt = row & 2047;
          size_t hbase = ((size_t)bb * 16 + head) * 131072;
          u16* qout = (u16*)outp;
          if (sec == 0) {
            qout[hbase + qk_off(tt, hd)] = f2b(v * scale);
          } else if (sec == 1) {
            (qout + 8388608)[hbase + qk_off(tt, hd)] = f2b(v);
          } else {
            (qout + 16777216)[hbase + v_off(tt, hd)] = f2b(v);
          }
        }
      }
    }
  }
}

// ---------------------------------------------------------------------------
// Flash attention v4 (unchanged). Causal, Q pre-scaled by log2e/32.
__global__ __launch_bounds__(256) void attn_kernel(
    const u16* __restrict__ Q, const u16* __restrict__ Kc,
    const u16* __restrict__ Vt, const float* __restrict__ x,
    float* __restrict__ x1, u16* __restrict__ xb1) {
  const int bh = blockIdx.x & 63;
  const int slot = blockIdx.x >> 6;
  const int tid = threadIdx.x;
  const int wid = tid >> 6, lane = tid & 63;
  const int g = lane >> 4, c = lane & 15;
  const u16* Qh = Q + (size_t)bh * 131072;
  const u16* Kh = Kc + (size_t)bh * 131072;
  const u16* Vh = Vt + (size_t)bh * 131072;
  const int b = bh >> 4, head = bh & 15;

  __shared__ __attribute__((aligned(16))) u16 Ks[8192];
  __shared__ __attribute__((aligned(16))) u16 Vs[8192];
  __shared__ __attribute__((aligned(16))) u16 P[4][32][72];

  bf16x8 ones;
#pragma unroll
  for (int i = 0; i < 8; i++) ones[i] = (__bf16)1.0f;

  const f32x4 zero4 = {0.f, 0.f, 0.f, 0.f};

  for (int phase = 0; phase < 2; ++phase) {
    const int bt = phase ? (15 - slot) : slot;
    const int q0b = bt * 128;
    const int q0 = q0b + wid * 32;
    const int kendw = q0 + 32;
    const int nkt = bt + 1;

    bf16x8 qf[2][2];
#pragma unroll
    for (int mt = 0; mt < 2; mt++)
#pragma unroll
      for (int h = 0; h < 2; h++)
        qf[mt][h] = *(const bf16x8*)&Qh[(((q0 >> 4) + mt) * 2 + h) * 512 + lane * 8];

    f32x4 o[2][4];
    f32x4 lac[2];
#pragma unroll
    for (int mt = 0; mt < 2; mt++) {
      lac[mt] = zero4;
#pragma unroll
      for (int i = 0; i < 4; i++) o[mt][i] = zero4;
    }

    for (int kt = 0; kt < nkt; ++kt) {
      const int k0 = kt * 128;
#pragma unroll
      for (int r2 = 0; r2 < 4; r2++) {
        int idx = (r2 * 256 + tid) * 8;
        gld16(Kh + (size_t)k0 * 64 + idx, Ks + idx);
        gld16(Vh + (size_t)k0 * 64 + idx, Vs + idx);
      }
      __syncthreads();

#pragma unroll
      for (int s2 = 0; s2 < 2; ++s2) {
        const int k0s = k0 + s2 * 64;
        if (k0s < kendw) {
          bf16x8 kf[4][2], vf[4][2];
#pragma unroll
          for (int nt = 0; nt < 4; nt++)
#pragma unroll
            for (int h = 0; h < 2; h++) {
              kf[nt][h] = *(const bf16x8*)&Ks[s2 * 4096 + (nt * 2 + h) * 512 + lane * 8];
              vf[nt][h] = *(const bf16x8*)&Vs[s2 * 4096 + (nt * 2 + h) * 512 + lane * 8];
            }

          f32x4 sv[2][4];
#pragma unroll
          for (int mt = 0; mt < 2; mt++)
#pragma unroll
            for (int nt = 0; nt < 4; nt++) sv[mt][nt] = zero4;
#pragma unroll
          for (int nt = 0; nt < 4; nt++)
#pragma unroll
            for (int mt = 0; mt < 2; mt++) {
              sv[mt][nt] = MFMA(qf[mt][0], kf[nt][0], sv[mt][nt]);
              sv[mt][nt] = MFMA(qf[mt][1], kf[nt][1], sv[mt][nt]);
            }

          if (k0s + 64 > q0) {
#pragma unroll
            for (int mt = 0; mt < 2; mt++)
#pragma unroll
              for (int rr = 0; rr < 4; rr++) {
                int q = q0 + mt * 16 + g * 4 + rr;
#pragma unroll
                for (int nt = 0; nt < 4; nt++)
                  if (k0s + nt * 16 + c > q) sv[mt][nt][rr] = -1e30f;
              }
          }

#pragma unroll
          for (int mt = 0; mt < 2; mt++)
#pragma unroll
            for (int rr = 0; rr < 4; rr++) {
              union { u16x4 u; bf16x4 h; } pw;
#pragma unroll
              for (int nt = 0; nt < 4; nt++)
                pw.h[nt] = (__bf16)__builtin_amdgcn_exp2f(sv[mt][nt][rr]);
              *(u16x4*)&P[wid][mt * 16 + g * 4 + rr][4 * c] = pw.u;
            }

          asm volatile("s_waitcnt lgkmcnt(0)" ::: "memory");

#pragma unroll
          for (int mt = 0; mt < 2; mt++) {
            bf16x8 pf0 = *(const bf16x8*)&P[wid][mt * 16 + c][g * 8];
            bf16x8 pf1 = *(const bf16x8*)&P[wid][mt * 16 + c][32 + g * 8];
            lac[mt] = MFMA(pf0, ones, lac[mt]);
            lac[mt] = MFMA(pf1, ones, lac[mt]);
#pragma unroll
            for (int ot = 0; ot < 4; ot++) {
              f32x4 oo = MFMA(pf0, vf[ot][0], o[mt][ot]);
              o[mt][ot] = MFMA(pf1, vf[ot][1], oo);
            }
          }
        }
      }
      __syncthreads();
    }

    float inv[2][4];
#pragma unroll
    for (int mt = 0; mt < 2; mt++)
#pragma unroll
      for (int rr = 0; rr < 4; rr++) inv[mt][rr] = 1.0f / lac[mt][rr];
#pragma unroll
    for (int mt = 0; mt < 2; mt++)
#pragma unroll
      for (int ot = 0; ot < 4; ot++)
#pragma unroll
        for (int rr = 0; rr < 4; rr++) {
          int t = q0 + mt * 16 + g * 4 + rr;
          int hd = ot * 16 + c;
          size_t xi = ((size_t)b * 2048 + t) * 1024 + head * 64 + hd;
          float v = x[xi] + o[mt][ot][rr] * inv[mt][rr];
          x1[xi] = v;
          xb1[xi] = f2b(v);
        }
  }
}

// ---------------------------------------------------------------------------
extern "C" void kernel_launch(void* const* d_in, const int* in_sizes, int n_in,
                              void* d_out, int out_size, void* d_ws, size_t ws_size,
                              hipStream_t stream) {
  (void)in_sizes; (void)n_in; (void)out_size; (void)ws_size;
  const float* x = (const float*)d_in[0];
  const float* Wq = (const float*)d_in[1];
  const float* bq = (const float*)d_in[2];
  const float* Wk = (const float*)d_in[3];
  const float* bk = (const float*)d_in[4];
  const float* Wv = (const float*)d_in[5];
  const float* bv = (const float*)d_in[6];
  const float* W1 = (const float*)d_in[7];
  const float* b1 = (const float*)d_in[8];
  const float* W2 = (const float*)d_in[9];
  const float* b2 = (const float*)d_in[10];

  char* ws = (char*)d_ws;
  size_t off = 0;
  auto alloc = [&](size_t bytes) {
    char* p = ws + off;
    off += (bytes + 255) & ~(size_t)255;
    return p;
  };
  u16* xb    = (u16*)alloc(8192ull * 1024 * 2);   // bf16(x)
  u16* Wqkvt = (u16*)alloc(3072ull * 1024 * 2);   // [3072][1024] bf16 (Wq|Wk|Wv rows)
  u16* W1t   = (u16*)alloc(4096ull * 1024 * 2);
  u16* W2t   = (u16*)alloc(1024ull * 4096 * 2);
  u16* Qb    = (u16*)alloc(3ull * 8192 * 1024 * 2);  // Q|K|V frag-ordered, contiguous
  float* x1  = (float*)alloc(8192ull * 1024 * 4); // x + attn (fp32 residual)
  u16* hb    = (u16*)alloc(8192ull * 4096 * 2);   // gelu(x1@W1+b1)
  u16* xb1   = xb;  // xb dead after QKV gemm; reuse for bf16(x1)
  u16* Kb    = Qb + 8388608;
  u16* Vtb   = Qb + 16777216;

  const float qscale = 1.4426950408889634f / 32.0f;  // log2e / sqrt(H)

  // 1. x -> bf16
  xconv<<<dim3(8192), dim3(256), 0, stream>>>(x, xb, 8192 * 1024);
  // 2. all weight transposes in one launch
  wtrans_all<<<dim3(11264), dim3(32, 8), 0, stream>>>(
      Wq, Wk, Wv, W1, W2, Wqkvt, W1t, W2t);
  // 3. fused QKV projection (M=8192, N=3072, K=1024) -> frag-ordered Q/K/V
  //    256x128 tiles: 32 x 24 = 768 blocks
  gemm256<4><<<dim3(768), dim3(512), 0, stream>>>(
      xb, Wqkvt, bq, bk, bv, Qb, nullptr, 3072, 1024, qscale);
  // 4. attention + residual 1  (512 blocks; paired 128-row tiles)
  attn_kernel<<<dim3(512), dim3(256), 0, stream>>>(Qb, Kb, Vtb, x, x1, xb1);
  // 5. MLP1: gelu(x1 @ W1 + b1)  (M=8192, N=4096, K=1024): 32 x 32 = 1024 blocks
  gemm256<2><<<dim3(1024), dim3(512), 0, stream>>>(
      xb1, W1t, b1, nullptr, nullptr, hb, nullptr, 4096, 1024, 1.0f);
  // 6. MLP2 + residual 2 -> d_out (fp32) (M=8192, N=1024, K=4096): 32 x 8 = 256
  //    blocks = exactly 1 block/CU, one clean round, 64 K-tiles of pipeline.
  gemm256<3><<<dim3(256), dim3(512), 0, stream>>>(
      hb, W2t, b2, nullptr, nullptr, d_out, x1, 1024, 4096, 1.0f);
}